// Round 7
// baseline (731.015 us; speedup 1.0000x reference)
//
#include <hip/hip_runtime.h>

// OnlineDenoisingAutoencoder: LSTM(B=2048, T=2048, in=1, proj=16, H=32)
// R7 = R6 minus the LDS h round-trip. 2 batches/wave (half=batch, j=lane&31),
// all 4 gates per lane, v_dot2_f32_f16 dots, fp32 cell state.
// h all-gather is now in-register: 1 ds_swizzle(xor16) + v_perm pack + 15 DPP
// movs produce 16 packed-fp16 regs per lane (~40 cyc, VALU) instead of
// ds_write + 4x ds_read_b128 (~240 cyc ordered DS chain, exposed at TLP=1).
// The network's lane-dependent k-order is self-discovered at setup by pushing
// (float)j through the SAME network and loading W_hh in that order.
// History: R2 LDS-pipe-bound 864us; R3 pk_fma not 2x (996); R4 readlane 2x
// modeled cost (1034); R6 fdot2+2batch/wave 670us, TLP=1 latency-exposed.

#define BB 2048
#define TT 2048
#define HH 32

typedef _Float16 h2 __attribute__((ext_vector_type(2)));

__device__ __forceinline__ float gate_eval(float x, float m, float a, float b) {
    // a * (1 / (1 + 2^(m*x))) + b ; sigmoid: m=-log2e,a=1,b=0 ; tanh: m=-2log2e,a=2,b=-1
    float e = __builtin_amdgcn_exp2f(x * m);
    float r = __builtin_amdgcn_rcpf(1.0f + e);
    return fmaf(a, r, b);
}

template <int CTRL>
__device__ __forceinline__ int dpp_mov(int v) {
    return __builtin_amdgcn_update_dpp(0, v, CTRL, 0xf, 0xf, true);
}

template <int CTRL>
__device__ __forceinline__ float dpp_add(float v) {
    int s = __builtin_amdgcn_update_dpp(0, __float_as_int(v), CTRL, 0xf, 0xf, true);
    return v + __int_as_float(s);
}

struct HVec { int v[16]; };   // 16 x packed fp16 pair

// All-gather one fp32 value per lane (within each 32-lane half) into 16 packed
// fp16 pairs. Ordering is arbitrary-but-fixed per lane; weights are loaded
// through the same network at setup, so any consistent permutation is correct.
__device__ __forceinline__ HVec gather_net(float h) {
    _Float16 hf = (_Float16)h;                                // RTN, same as R6
    unsigned hb = (unsigned)__builtin_bit_cast(unsigned short, hf);
    int dup = (int)(hb | (hb << 16));                         // [h16|h16]
    int prt = __builtin_amdgcn_ds_swizzle(dup, 0x401F);       // lane ^ 16 (reg shuffle)
    HVec r;
    // bytes[0,1] = own h16, bytes[2,3] = partner h16
    r.v[0] = (int)__builtin_amdgcn_perm((unsigned)prt, (unsigned)dup, 0x07060100u);
    r.v[1] = dpp_mov<0xB1>(r.v[0]);                           // quad_perm xor1
    r.v[2] = dpp_mov<0x4E>(r.v[0]);                           // quad_perm xor2
    r.v[3] = dpp_mov<0x4E>(r.v[1]);
    r.v[4] = dpp_mov<0x124>(r.v[0]);                          // row_ror:4
    r.v[5] = dpp_mov<0x124>(r.v[1]);
    r.v[6] = dpp_mov<0x124>(r.v[2]);
    r.v[7] = dpp_mov<0x124>(r.v[3]);
    r.v[8]  = dpp_mov<0x128>(r.v[0]);                         // row_ror:8 (== xor8)
    r.v[9]  = dpp_mov<0x128>(r.v[1]);
    r.v[10] = dpp_mov<0x128>(r.v[2]);
    r.v[11] = dpp_mov<0x128>(r.v[3]);
    r.v[12] = dpp_mov<0x128>(r.v[4]);
    r.v[13] = dpp_mov<0x128>(r.v[5]);
    r.v[14] = dpp_mov<0x128>(r.v[6]);
    r.v[15] = dpp_mov<0x128>(r.v[7]);
    return r;
}

__global__ __launch_bounds__(256) void lstm_fused_kernel(
    const float* __restrict__ x_seq,  // [B,T,1]
    const float* __restrict__ Wp,     // [16,1]
    const float* __restrict__ bp,     // [16]
    const float* __restrict__ W_ih,   // [128,16]
    const float* __restrict__ W_hh,   // [128,32]
    const float* __restrict__ b_ih,   // [128]
    const float* __restrict__ b_hh,   // [128]
    const float* __restrict__ Wo,     // [1,32]
    const float* __restrict__ bo,     // [1]
    float* __restrict__ out)          // [B,T,1] fp32
{
    const int tid  = threadIdx.x;
    const int wave = tid >> 6;
    const int lane = tid & 63;
    const int half = lane >> 5;      // which of the wave's 2 batch elements
    const int j    = lane & 31;      // hidden index this lane owns
    const int b    = blockIdx.x * 8 + wave * 2 + half;

    // PyTorch gate row order: i=[0,32), f=[32,64), g=[64,96), o=[96,128)
    const int rI = j, rF = HH + j, rG = 2 * HH + j, rO = 3 * HH + j;

    // ---- discover this lane's gather ordering, load W_hh in that order ----
    HVec idx = gather_net((float)j);   // fp16 holds small ints exactly
    h2 wI[16], wF[16], wG[16], wO[16];
    {
        const float* pI = W_hh + rI * HH;
        const float* pF = W_hh + rF * HH;
        const float* pG = W_hh + rG * HH;
        const float* pO = W_hh + rO * HH;
#pragma unroll
        for (int s = 0; s < 16; ++s) {
            h2 iv = __builtin_bit_cast(h2, idx.v[s]);
            int kx = (int)(float)iv.x;
            int ky = (int)(float)iv.y;
            wI[s].x = (_Float16)pI[kx]; wI[s].y = (_Float16)pI[ky];
            wF[s].x = (_Float16)pF[kx]; wF[s].y = (_Float16)pF[ky];
            wG[s].x = (_Float16)pG[kx]; wG[s].y = (_Float16)pG[ky];
            wO[s].x = (_Float16)pO[kx]; wO[s].y = (_Float16)pO[ky];
        }
    }

    // ---- collapse input pipeline: gate pre-act = dot + x*a + c (INPUT_DIM==1) ----
    float aI = 0.f, cI = 0.f, aF = 0.f, cF = 0.f;
    float aG = 0.f, cG = 0.f, aO = 0.f, cO = 0.f;
#pragma unroll
    for (int p = 0; p < 16; ++p) {
        float wpv = Wp[p], bpv = bp[p];
        float wi = W_ih[rI * 16 + p], wf = W_ih[rF * 16 + p];
        float wg = W_ih[rG * 16 + p], wo_ = W_ih[rO * 16 + p];
        aI = fmaf(wi, wpv, aI);  cI = fmaf(wi, bpv, cI);
        aF = fmaf(wf, wpv, aF);  cF = fmaf(wf, bpv, cF);
        aG = fmaf(wg, wpv, aG);  cG = fmaf(wg, bpv, cG);
        aO = fmaf(wo_, wpv, aO); cO = fmaf(wo_, bpv, cO);
    }
    cI += b_ih[rI] + b_hh[rI];
    cF += b_ih[rF] + b_hh[rF];
    cG += b_ih[rG] + b_hh[rG];
    cO += b_ih[rO] + b_hh[rO];

    const float LOG2E = 1.44269504088896340736f;
    const float woj = Wo[j];
    const float bo0 = bo[0];

    float c = 0.0f;
    const float* xp = x_seq + (size_t)b * TT;
    float* op = out + (size_t)b * TT;

    HVec hcur;
#pragma unroll
    for (int s = 0; s < 16; ++s) hcur.v[s] = 0;   // h0 = 0

    float4 x4 = *(const float4*)(xp);

    for (int t = 0; t < TT; t += 4) {
        const int tn = (t + 4 < TT) ? (t + 4) : t;
        float4 x4n = *(const float4*)(xp + tn);   // prefetch next group
        float outv[4];
#pragma unroll
        for (int u = 0; u < 4; ++u) {
            float xv = (u == 0) ? x4.x : (u == 1) ? x4.y : (u == 2) ? x4.z : x4.w;

            // 4 gate dots over h (fp16 inputs, fp32 accum), 2 accumulators each
            float sI0 = cI, sI1 = xv * aI;
            float sF0 = cF, sF1 = xv * aF;
            float sG0 = cG, sG1 = xv * aG;
            float sO0 = cO, sO1 = xv * aO;
#pragma unroll
            for (int k = 0; k < 16; k += 2) {
                h2 h0 = __builtin_bit_cast(h2, hcur.v[k]);
                h2 h1 = __builtin_bit_cast(h2, hcur.v[k + 1]);
                sI0 = __builtin_amdgcn_fdot2(wI[k],     h0, sI0, false);
                sF0 = __builtin_amdgcn_fdot2(wF[k],     h0, sF0, false);
                sG0 = __builtin_amdgcn_fdot2(wG[k],     h0, sG0, false);
                sO0 = __builtin_amdgcn_fdot2(wO[k],     h0, sO0, false);
                sI1 = __builtin_amdgcn_fdot2(wI[k + 1], h1, sI1, false);
                sF1 = __builtin_amdgcn_fdot2(wF[k + 1], h1, sF1, false);
                sG1 = __builtin_amdgcn_fdot2(wG[k + 1], h1, sG1, false);
                sO1 = __builtin_amdgcn_fdot2(wO[k + 1], h1, sO1, false);
            }

            float iv = gate_eval(sI0 + sI1, -LOG2E, 1.0f, 0.0f);
            float fv = gate_eval(sF0 + sF1, -LOG2E, 1.0f, 0.0f);
            float gv = gate_eval(sG0 + sG1, -2.0f * LOG2E, 2.0f, -1.0f);
            float ov = gate_eval(sO0 + sO1, -LOG2E, 1.0f, 0.0f);

            c = fmaf(fv, c, iv * gv);
            float th = gate_eval(c, -2.0f * LOG2E, 2.0f, -1.0f); // tanh(c)
            float h = ov * th;

            // in-register all-gather of h for the next step (no LDS memory)
            hcur = gather_net(h);

            // fused output projection: width-32 reduce on VALU via DPP.
            float po = woj * h;
            po = dpp_add<0x111>(po);
            po = dpp_add<0x112>(po);
            po = dpp_add<0x114>(po);
            po = dpp_add<0x118>(po);
            po = dpp_add<0x142>(po);   // row_bcast15 -> lane 31/63 hold the sum
            outv[u] = po + bo0;
        }
        if ((lane & 31) == 31) {
            *(float4*)(op + t) = make_float4(outv[0], outv[1], outv[2], outv[3]);
        }
        x4 = x4n;
    }
}

extern "C" void kernel_launch(void* const* d_in, const int* in_sizes, int n_in,
                              void* d_out, int out_size, void* d_ws, size_t ws_size,
                              hipStream_t stream) {
    const float* x_seq = (const float*)d_in[0];
    const float* Wp    = (const float*)d_in[1];
    const float* bp    = (const float*)d_in[2];
    const float* W_ih  = (const float*)d_in[3];
    const float* W_hh  = (const float*)d_in[4];
    const float* b_ih  = (const float*)d_in[5];
    const float* b_hh  = (const float*)d_in[6];
    const float* Wo    = (const float*)d_in[7];
    const float* bo    = (const float*)d_in[8];
    float* out = (float*)d_out;

    dim3 grid(BB / 8);   // 4 waves/block, 2 batch elements/wave
    dim3 block(256);
    lstm_fused_kernel<<<grid, block, 0, stream>>>(
        x_seq, Wp, bp, W_ih, W_hh, b_ih, b_hh, Wo, bo, out);
}